// Round 1
// baseline (514.185 us; speedup 1.0000x reference)
//
#include <hip/hip_runtime.h>
#include <hip/hip_bf16.h>

#define B_  64
#define R_  512
#define M_  256
#define A_  256
#define L_  4096

typedef float    f32x4 __attribute__((ext_vector_type(4)));
typedef _Float16 f16x8 __attribute__((ext_vector_type(8)));

// ---------------- kernel 1: q = h @ Wa^T + ba ----------------
// grid 64 (b), 256 threads. Each wave produces 64 q-entries via coalesced
// Wa-row reads + full-wave shuffle reduction.
__global__ __launch_bounds__(256) void k_q(const float* __restrict__ h,
                                           const float* __restrict__ Wa,
                                           const float* __restrict__ ba,
                                           float* __restrict__ q) {
  int b = blockIdx.x;
  int tid = threadIdx.x;
  int wv = tid >> 6, lane = tid & 63;
  const f32x4* hp = (const f32x4*)(h + (size_t)b * R_ + lane * 8);
  f32x4 h0 = hp[0], h1 = hp[1];
#pragma unroll 4
  for (int i = 0; i < 64; ++i) {
    int a = wv * 64 + i;
    const f32x4* wp = (const f32x4*)(Wa + (size_t)a * R_ + lane * 8);
    f32x4 w0 = wp[0], w1 = wp[1];
    f32x4 pr = h0 * w0 + h1 * w1;
    float p = (pr.x + pr.y) + (pr.z + pr.w);
#pragma unroll
    for (int m = 1; m < 64; m <<= 1) p += __shfl_xor(p, m);
    if (lane == 0) q[b * A_ + a] = p + ba[a];
  }
}

// ---------------- kernel 2: e[b][l] = tanh(q + fv@Ua^T) @ w ----------------
// grid 2048 = 64 b x 32 l-tiles of 128. 256 threads (4 waves x 32 rows).
// fv rows live as fp16 A-fragments in registers (full K=256).
// Ua staged to LDS fp16 in 4 chunks of 64 A-cols; epilogue per chunk.
__global__ __launch_bounds__(256) void k_e(const float* __restrict__ fv,
                                           const float* __restrict__ Ua,
                                           const float* __restrict__ q,
                                           const float* __restrict__ w,
                                           float* __restrict__ e) {
  __shared__ __align__(16) _Float16 sUa[64][264];   // 64 a-rows x 256 m, +8 pad
  __shared__ float sq[A_];
  __shared__ float sw[A_];
  int tid = threadIdx.x;
  int b  = blockIdx.x >> 5;
  int l0 = (blockIdx.x & 31) * 128;
  int wv = tid >> 6, lane = tid & 63;
  int quad = lane >> 4, l16 = lane & 15;

  sq[tid] = q[b * A_ + tid];
  sw[tid] = w[tid];

  // A fragments: A[m=lane&15][k=quad*8+j]; rows = l0+wv*32+rs*16+l16
  f16x8 afrag[2][8];
#pragma unroll
  for (int rs = 0; rs < 2; ++rs) {
    const float* rowp = fv + ((size_t)b * L_ + (size_t)(l0 + wv * 32 + rs * 16 + l16)) * M_ + quad * 8;
#pragma unroll
    for (int s = 0; s < 8; ++s) {
      f32x4 x = *(const f32x4*)(rowp + s * 32);
      f32x4 y = *(const f32x4*)(rowp + s * 32 + 4);
      f16x8 f;
      f[0] = (_Float16)x.x; f[1] = (_Float16)x.y; f[2] = (_Float16)x.z; f[3] = (_Float16)x.w;
      f[4] = (_Float16)y.x; f[5] = (_Float16)y.y; f[6] = (_Float16)y.z; f[7] = (_Float16)y.w;
      afrag[rs][s] = f;
    }
  }

  float eacc[2][4] = {{0.f, 0.f, 0.f, 0.f}, {0.f, 0.f, 0.f, 0.f}};

  for (int c = 0; c < 4; ++c) {
    __syncthreads();
    // stage Ua rows [c*64, c*64+64) as fp16 into LDS
    {
      int row = tid >> 2, seg = tid & 3;
      const float* src = Ua + (size_t)(c * 64 + row) * M_ + seg * 64;
      _Float16* dst = &sUa[row][seg * 64];
#pragma unroll
      for (int j = 0; j < 16; ++j) {
        f32x4 v = *(const f32x4*)(src + j * 4);
        dst[j * 4 + 0] = (_Float16)v.x; dst[j * 4 + 1] = (_Float16)v.y;
        dst[j * 4 + 2] = (_Float16)v.z; dst[j * 4 + 3] = (_Float16)v.w;
      }
    }
    __syncthreads();

    f32x4 acc[2][4];
#pragma unroll
    for (int rs = 0; rs < 2; ++rs)
#pragma unroll
      for (int t = 0; t < 4; ++t) acc[rs][t] = 0.f;

#pragma unroll
    for (int s = 0; s < 8; ++s) {
#pragma unroll
      for (int t = 0; t < 4; ++t) {
        // B[k=quad*8+j][n=l16] = Ua[a0+l16][s*32+quad*8+j] (contiguous 16B)
        f16x8 bfrag = *(const f16x8*)(&sUa[t * 16 + l16][s * 32 + quad * 8]);
        acc[0][t] = __builtin_amdgcn_mfma_f32_16x16x32_f16(afrag[0][s], bfrag, acc[0][t], 0, 0, 0);
        acc[1][t] = __builtin_amdgcn_mfma_f32_16x16x32_f16(afrag[1][s], bfrag, acc[1][t], 0, 0, 0);
      }
    }

    // epilogue for this chunk: eacc += tanh(q + k) * w ; C/D: col=l16, row=quad*4+i
#pragma unroll
    for (int rs = 0; rs < 2; ++rs)
#pragma unroll
      for (int t = 0; t < 4; ++t) {
        int col = c * 64 + t * 16 + l16;
        float qc = sq[col], wc = sw[col];
#pragma unroll
        for (int i = 0; i < 4; ++i) {
          float x = qc + acc[rs][t][i];
          float ex = __expf(2.0f * x);                       // tanh = 1 - 2/(e^2x+1)
          float th = 1.0f - 2.0f * __builtin_amdgcn_rcpf(ex + 1.0f);
          eacc[rs][i] += th * wc;
        }
      }
  }

  // sum over the 16 column-lanes, write e
#pragma unroll
  for (int rs = 0; rs < 2; ++rs)
#pragma unroll
    for (int i = 0; i < 4; ++i) {
      float v = eacc[rs][i];
      v += __shfl_xor(v, 1); v += __shfl_xor(v, 2);
      v += __shfl_xor(v, 4); v += __shfl_xor(v, 8);
      if (l16 == 0)
        e[(size_t)b * L_ + l0 + wv * 32 + rs * 16 + quad * 4 + i] = v;
    }
}

// ---------------- kernel 3: attn = softmax_L(e) ----------------
__global__ __launch_bounds__(256) void k_softmax(const float* __restrict__ e,
                                                 float* __restrict__ attn) {
  __shared__ float red[8];
  int b = blockIdx.x, t = threadIdx.x;
  int wv = t >> 6, lane = t & 63;
  float v[16];
  float mx = -1e30f;
#pragma unroll
  for (int i = 0; i < 16; ++i) {
    v[i] = e[(size_t)b * L_ + i * 256 + t];
    mx = fmaxf(mx, v[i]);
  }
#pragma unroll
  for (int m = 1; m < 64; m <<= 1) mx = fmaxf(mx, __shfl_xor(mx, m));
  if (lane == 0) red[wv] = mx;
  __syncthreads();
  mx = fmaxf(fmaxf(red[0], red[1]), fmaxf(red[2], red[3]));
  float s = 0.f;
#pragma unroll
  for (int i = 0; i < 16; ++i) { v[i] = __expf(v[i] - mx); s += v[i]; }
#pragma unroll
  for (int m = 1; m < 64; m <<= 1) s += __shfl_xor(s, m);
  if (lane == 0) red[4 + wv] = s;
  __syncthreads();
  s = (red[4] + red[5]) + (red[6] + red[7]);
  float inv = 1.0f / s;
#pragma unroll
  for (int i = 0; i < 16; ++i) attn[(size_t)b * L_ + i * 256 + t] = v[i] * inv;
}

// ---------------- kernel 4: ctx[b][m] = sum_l attn*fv ----------------
// grid 1024 = 64 b x 16 l-chunks of 256. Coalesced float4 streaming of fv,
// LDS partials, one atomicAdd per (b,m) per block (16 per address total).
__global__ __launch_bounds__(256) void k_ctx(const float* __restrict__ fv,
                                             const float* __restrict__ attn,
                                             float* __restrict__ out) {
  __shared__ float sattn[256];
  __shared__ float part[4][256];
  int t = threadIdx.x;
  int b  = blockIdx.x >> 4;
  int l0 = (blockIdx.x & 15) * 256;
  int g = t >> 6, lane = t & 63;
  sattn[t] = attn[(size_t)b * L_ + l0 + t];
  __syncthreads();
  f32x4 acc = 0.f;
  const f32x4* base = (const f32x4*)(fv + ((size_t)b * L_ + l0) * M_) + lane;
#pragma unroll 4
  for (int l = g; l < 256; l += 4) {
    acc += sattn[l] * base[(size_t)l * (M_ / 4)];
  }
  ((f32x4*)part[g])[lane] = acc;
  __syncthreads();
  float sum = (part[0][t] + part[1][t]) + (part[2][t] + part[3][t]);
  atomicAdd(out + (size_t)b * M_ + t, sum);
}

extern "C" void kernel_launch(void* const* d_in, const int* in_sizes, int n_in,
                              void* d_out, int out_size, void* d_ws, size_t ws_size,
                              hipStream_t stream) {
  const float* h  = (const float*)d_in[0];   // [64, 512]
  const float* fv = (const float*)d_in[1];   // [64, 4096, 256]
  const float* Wa = (const float*)d_in[2];   // [256, 512]
  const float* Ua = (const float*)d_in[3];   // [256, 256]
  const float* w  = (const float*)d_in[4];   // [256, 1]
  const float* ba = (const float*)d_in[5];   // [1, 256]
  float* out = (float*)d_out;                // [64, 256]

  char* ws = (char*)d_ws;
  float* q    = (float*)ws;                                  // 64*256*4   = 64 KB
  float* e    = (float*)(ws + (64 * 1024));                  // 64*4096*4  = 1 MB
  float* attn = (float*)(ws + (64 * 1024) + (1024 * 1024));  // 1 MB

  hipMemsetAsync(d_out, 0, (size_t)B_ * M_ * sizeof(float), stream);
  k_q<<<dim3(B_), dim3(256), 0, stream>>>(h, Wa, ba, q);
  k_e<<<dim3(B_ * (L_ / 128)), dim3(256), 0, stream>>>(fv, Ua, q, w, e);
  k_softmax<<<dim3(B_), dim3(256), 0, stream>>>(e, attn);
  k_ctx<<<dim3(B_ * 16), dim3(256), 0, stream>>>(fv, attn, out);
}